// Round 19
// baseline (147.048 us; speedup 1.0000x reference)
//
#include <hip/hip_runtime.h>
#include <cstdint>
#include <cstddef>

#define B_SZ 2
#define N_SEQ 32768
#define NB 2048
#define HD 32
#define LQ 16
#define KCNT 17
#define M_ROWS 65536
#define SCALE_F 0.17677669529663687f /* 32^-0.5 */

typedef __attribute__((ext_vector_type(8))) short sv8;
typedef __attribute__((ext_vector_type(4))) short sv4;
typedef __attribute__((ext_vector_type(4))) float f4;

__device__ __forceinline__ short f2bf(float f) {
  unsigned u = __builtin_bit_cast(unsigned, f);
  u = (u + 0x7FFFu + ((u >> 16) & 1u)) >> 16;
  return (short)u;
}
__device__ __forceinline__ float bf2f(short s) {
  unsigned u = ((unsigned)(unsigned short)s) << 16;
  return __builtin_bit_cast(float, u);
}
__device__ __forceinline__ void gload16(const void* g, void* l) {
  __builtin_amdgcn_global_load_lds(
      (const __attribute__((address_space(1))) unsigned int*)g,
      (__attribute__((address_space(3))) unsigned int*)l, 16, 0, 0);
}
__device__ __forceinline__ f4 mfma16(sv8 a, sv8 b, f4 c) {
  return __builtin_amdgcn_mfma_f32_16x16x32_bf16(a, b, c, 0, 0, 0);
}

// fused prep: cast X (4194304 f4), Wqkv (49152 f4), Wproj (16384 f4) to bf16
__global__ __launch_bounds__(256) void cast_all(
    const float* __restrict__ x, const float* __restrict__ wq,
    const float* __restrict__ wp, short* __restrict__ X1,
    short* __restrict__ W1, short* __restrict__ WP1) {
  const int i = blockIdx.x * 256 + threadIdx.x;
  const float* src;
  short* dst;
  int off;
  if (i < 4194304) { src = x; dst = X1; off = i; }
  else if (i < 4194304 + 49152) { src = wq; dst = W1; off = i - 4194304; }
  else if (i < 4194304 + 49152 + 16384) { src = wp; dst = WP1; off = i - 4194304 - 49152; }
  else return;
  float4 v = ((const float4*)src)[off];
  sv4 h = {f2bf(v.x), f2bf(v.y), f2bf(v.z), f2bf(v.w)};
  *(sv4*)&dst[(size_t)off * 4] = h;
}

// ---- QKV GEMM: 2-buffer counted-vmcnt K-loop + LDS-staged coalesced
// epilogue (round-18 proven). ----
__global__ __launch_bounds__(256) void gemm_bf_qkv(
    const short* __restrict__ A1, const short* __restrict__ B1,
    const float* __restrict__ bias, short* __restrict__ Qbf,
    short* __restrict__ Kbf, short* __restrict__ Vbf) {
  __shared__ __align__(16) short LB[2][2][128][32];  // [buf][A|B][row][col]
  const int tid = threadIdx.x;
  const int w = tid >> 6, l = tid & 63;
  const int wm = w >> 1, wn = w & 1;
  const int bid = blockIdx.x;
  const int chunkc = (6 * 512) >> 3;
  const int lbid = (bid & 7) * chunkc + (bid >> 3);
  const int nti = lbid % 6, mti = lbid / 6;
  const int m0 = mti * 128, n0 = nti * 128;
  const int lr = l >> 2, lc = (l & 3) * 8;
  const int fr = l & 15, kg = (l >> 4) * 8;
  f4 acc[4][4] = {};
#pragma unroll
  for (int i = 0; i < 2; ++i) {
    const int row = w * 32 + i * 16;
    gload16(A1 + (size_t)(m0 + row + lr) * 256 + lc, (void*)&LB[0][0][row][0]);
    gload16(B1 + (size_t)(n0 + row + lr) * 256 + lc, (void*)&LB[0][1][row][0]);
  }
  asm volatile("s_waitcnt vmcnt(0)" ::: "memory");
  __builtin_amdgcn_s_barrier();
  int cur = 0;
  for (int s = 0; s < 8; ++s) {
    if (s < 7) {
      const int sk = (s + 1) * 32;
#pragma unroll
      for (int i = 0; i < 2; ++i) {
        const int row = w * 32 + i * 16;
        gload16(A1 + (size_t)(m0 + row + lr) * 256 + sk + lc,
                (void*)&LB[cur ^ 1][0][row][0]);
        gload16(B1 + (size_t)(n0 + row + lr) * 256 + sk + lc,
                (void*)&LB[cur ^ 1][1][row][0]);
      }
    }
    if (s > 0) {
      if (s < 7) asm volatile("s_waitcnt vmcnt(4)" ::: "memory");
      else asm volatile("s_waitcnt vmcnt(0)" ::: "memory");
      __builtin_amdgcn_s_barrier();
    }
    sv8 fa[4], fb[4];
#pragma unroll
    for (int t = 0; t < 4; ++t) {
      fa[t] = *(const sv8*)&LB[cur][0][wm * 64 + t * 16 + fr][kg];
      fb[t] = *(const sv8*)&LB[cur][1][wn * 64 + t * 16 + fr][kg];
    }
#pragma unroll
    for (int mt = 0; mt < 4; ++mt)
#pragma unroll
      for (int nt2 = 0; nt2 < 4; ++nt2)
        acc[mt][nt2] = mfma16(fa[mt], fb[nt2], acc[mt][nt2]);
    asm volatile("s_waitcnt lgkmcnt(0)" ::: "memory");
    __builtin_amdgcn_s_barrier();
    cur ^= 1;
  }
  short* Lout = &LB[0][0][0][0];  // 128x128 shorts = 32 KB
  const int r0 = (l >> 4) * 4;
#pragma unroll
  for (int mt = 0; mt < 4; ++mt)
#pragma unroll
    for (int nt2 = 0; nt2 < 4; ++nt2) {
      const int n = wn * 64 + nt2 * 16 + fr;
      const float bv = bias[n0 + n];
#pragma unroll
      for (int j = 0; j < 4; ++j) {
        const int m = wm * 64 + mt * 16 + r0 + j;
        Lout[m * 128 + (n ^ ((m & 7) << 3))] = f2bf(acc[mt][nt2][j] + bv);
      }
    }
  __builtin_amdgcn_s_barrier();
  short* dst = (nti < 2) ? Qbf : ((nti < 4) ? Kbf : Vbf);
  const int nnb = (nti & 1) * 128;
  const int rrow = tid >> 4, seg = (tid & 15) * 8;
#pragma unroll
  for (int p = 0; p < 8; ++p) {
    const int row = p * 16 + rrow;
    sv8 v = *(const sv8*)&Lout[row * 128 + (seg ^ ((row & 7) << 3))];
    *(sv8*)&dst[(size_t)(m0 + row) * 256 + nnb + seg] = v;
  }
}

// ---- attn_proj: MFMA attention + FUSED output projection.
// One block per (b,nb), 4 waves x 2 heads. After PV, O (16x256 bf16) lives
// in LDS; each wave computes its 64 output cols: C = O x Wproj^T via
// 32 MFMAs (A = O rows from LDS, B = Wproj rows from global, L2-hot since
// all 4096 blocks share the 128 KB). Result staged fp32 in the dead K/V
// LDS region -> fully coalesced float4 stores. Numerically identical to
// the old attn->gemm_proj1 path (same bf16 operands).
__global__ __launch_bounds__(256, 4) void attn_proj(
    const short* __restrict__ Qb, const short* __restrict__ Kb,
    const short* __restrict__ Vb, const int* __restrict__ amask,
    const float* __restrict__ efeat, const float* __restrict__ Wgate,
    const float* __restrict__ bgate, const short* __restrict__ WP1,
    const float* __restrict__ bproj, float* __restrict__ out) {
  __shared__ __align__(16) short Buf[12672];  // Kl|Vl|Ol, 16x264 each
  __shared__ float4 Es[LQ * KCNT];
  __shared__ int Ms[LQ * KCNT];
  short* Kl = Buf;
  short* Vl = Buf + 4224;
  short* Ol = Buf + 8448;
  float* Fl = (float*)Buf;  // after proj MFMAs: [16][260] fp32 (16.6 KB)

  const int tid = threadIdx.x, g = blockIdx.x;
  const int b = g >> 11, nb = g & (NB - 1);
  const size_t tok0 = (size_t)(b * N_SEQ + nb * LQ);
  const int w = tid >> 6, l = tid & 63;
  const int ln = l & 15, lg = l >> 4;
  const f4 fzero = {0.f, 0.f, 0.f, 0.f};

  sv8 qf[2];
#pragma unroll
  for (int hh = 0; hh < 2; ++hh) {
    const int h = w * 2 + hh;
    qf[hh] = *(const sv8*)(Qb + (tok0 + ln) * 256 + h * 32 + lg * 8);
  }

#pragma unroll
  for (int i = 0; i < 2; ++i) {
    const int f = tid + i * 256;
    const int t = f >> 5, c8 = (f & 31) * 8;
    *(sv8*)&Kl[t * 264 + c8] = *(const sv8*)(Kb + (tok0 + t) * 256 + c8);
    *(sv8*)&Vl[t * 264 + c8] = *(const sv8*)(Vb + (tok0 + t) * 256 + c8);
  }
  {
    const float4* esrc = (const float4*)(efeat + (size_t)nb * LQ * KCNT * 4);
    const int* msrc = amask + (size_t)nb * LQ * KCNT;
    Es[tid] = esrc[tid];
    Ms[tid] = msrc[tid];
    if (tid < LQ * KCNT - 256) {
      Es[256 + tid] = esrc[256 + tid];
      Ms[256 + tid] = msrc[256 + tid];
    }
  }
  __syncthreads();

  const int q = ln;
#pragma unroll
  for (int hh = 0; hh < 2; ++hh) {
    const int h = w * 2 + hh;
    sv8 ka = *(const sv8*)&Kl[ln * 264 + h * 32 + lg * 8];
    f4 sr = mfma16(ka, qf[hh], fzero);

    const float wg0 = Wgate[h * 4], wg1 = Wgate[h * 4 + 1];
    const float wg2 = Wgate[h * 4 + 2], wg3 = Wgate[h * 4 + 3];
    const float bg = bgate[h];

    float rs = sr[0] + sr[1] + sr[2] + sr[3];
    rs += __shfl_xor(rs, 16);
    rs += __shfl_xor(rs, 32);

    float s_[4], gt_[4];
    int vis_[4];
#pragma unroll
    for (int j = 0; j < 4; ++j) {
      const int kc = lg * 4 + j;
      float e0, e1, e2, e3;
      if (kc == q) { e0 = e1 = e2 = 0.f; e3 = 1.f; }
      else { float4 e = Es[q * KCNT + kc]; e0 = e.x; e1 = e.y; e2 = e.z; e3 = e.w; }
      const int m = Ms[q * KCNT + kc];
      vis_[j] = m;
      s_[j] = sr[j] * SCALE_F + e3;
      gt_[j] = m ? (e0 * wg0 + e1 * wg1 + e2 * wg2 + e3 * wg3 + bg) : 0.f;
    }
    const int m16 = Ms[q * KCNT + 16];
    const float s16 = rs * 0.0625f * SCALE_F + 1.0f;

    float mx = -1e30f;
#pragma unroll
    for (int j = 0; j < 4; ++j)
      if (vis_[j]) mx = fmaxf(mx, s_[j]);
    mx = fmaxf(mx, __shfl_xor(mx, 16));
    mx = fmaxf(mx, __shfl_xor(mx, 32));
    if (m16) mx = fmaxf(mx, s16);

    float p_[4], den = 0.f;
#pragma unroll
    for (int j = 0; j < 4; ++j) {
      p_[j] = vis_[j] ? __expf(s_[j] - mx) : 0.f;
      den += p_[j];
    }
    den += __shfl_xor(den, 16);
    den += __shfl_xor(den, 32);
    const float p16 = m16 ? __expf(s16 - mx) : 0.f;
    den += p16;
    const float inv = 1.f / den;
    const float gt16 = m16 ? (wg3 + bg) : 0.f;
    const float cb16 = (p16 * inv + gt16) * 0.0625f;
    float pc[4];
#pragma unroll
    for (int j = 0; j < 4; ++j) pc[j] = p_[j] * inv + gt_[j] + cb16;

    sv8 pa;
#pragma unroll
    for (int e = 0; e < 8; ++e) {
      const int kc = lg * 8 + e;
      const int src = ((kc >> 2) << 4) | q;
      const float v0 = __shfl(pc[e & 3], src);
      pa[e] = (kc < 16) ? f2bf(v0) : (short)0;
    }

#pragma unroll
    for (int t = 0; t < 2; ++t) {
      sv8 vb;
#pragma unroll
      for (int e = 0; e < 8; ++e) {
        const int vr = (lg * 8 + e) & 15;  // clamp: pa[e]=0 for kc>=16
        vb[e] = Vl[vr * 264 + h * 32 + t * 16 + ln];
      }
      f4 oacc = mfma16(pa, vb, fzero);
#pragma unroll
      for (int j = 0; j < 4; ++j)
        Ol[(lg * 4 + j) * 264 + h * 32 + t * 16 + ln] = f2bf(oacc[j]);
    }
  }
  __syncthreads();  // Ol complete; Kl/Vl dead from here

  // ---- fused proj: wave w owns out cols [w*64, w*64+64) ----
  f4 pacc[4] = {};
#pragma unroll
  for (int kc8 = 0; kc8 < 8; ++kc8) {
    sv8 a = *(const sv8*)&Ol[ln * 264 + kc8 * 32 + lg * 8];
#pragma unroll
    for (int nt = 0; nt < 4; ++nt) {
      sv8 bfr = *(const sv8*)(WP1 + (size_t)(w * 64 + nt * 16 + ln) * 256 +
                              kc8 * 32 + lg * 8);
      pacc[nt] = mfma16(a, bfr, pacc[nt]);
    }
  }
  // stage fp32 result in Fl[16][260] (Kl/Vl region; disjoint from Ol)
#pragma unroll
  for (int nt = 0; nt < 4; ++nt) {
    const int n = w * 64 + nt * 16 + ln;
    const float bv = bproj[n];
#pragma unroll
    for (int j = 0; j < 4; ++j) Fl[(lg * 4 + j) * 260 + n] = pacc[nt][j] + bv;
  }
  __syncthreads();
  // coalesced fp32 write-out: 16 rows x 1 KB
#pragma unroll
  for (int i = 0; i < 4; ++i) {
    const int idx = tid + i * 256;  // 0..1023
    const int row = idx >> 6, c4 = (idx & 63) * 4;
    *(float4*)(out + (tok0 + row) * 256 + c4) = *(const float4*)&Fl[row * 260 + c4];
  }
}

extern "C" void kernel_launch(void* const* d_in, const int* in_sizes, int n_in,
                              void* d_out, int out_size, void* d_ws, size_t ws_size,
                              hipStream_t stream) {
  const float* x = (const float*)d_in[0];
  const int* amask = (const int*)d_in[1];
  const float* efeat = (const float*)d_in[2];
  const float* Wqkv = (const float*)d_in[3];
  const float* bqkv = (const float*)d_in[4];
  const float* Wproj = (const float*)d_in[5];
  const float* bproj = (const float*)d_in[6];
  const float* Wgate = (const float*)d_in[7];
  const float* bgate = (const float*)d_in[8];
  float* out = (float*)d_out;

  char* ws = (char*)d_ws;
  const size_t QB_SZ = (size_t)M_ROWS * 256 * 2;  // 32 MiB each
  const size_t W1_SZ = (size_t)768 * 256 * 2;     // 384 KiB
  const size_t WP1_SZ = (size_t)256 * 256 * 2;    // 128 KiB
  if (ws_size < 4 * QB_SZ + W1_SZ + WP1_SZ) return;

  short* X1 = (short*)ws;
  short* Qbf = (short*)(ws + QB_SZ);
  short* Kbf = (short*)(ws + 2 * QB_SZ);
  short* Vbf = (short*)(ws + 3 * QB_SZ);
  short* W1 = (short*)(ws + 4 * QB_SZ);
  short* WP1 = (short*)(ws + 4 * QB_SZ + W1_SZ);

  const int total_f4 = 4194304 + 49152 + 16384;
  cast_all<<<dim3((total_f4 + 255) / 256), 256, 0, stream>>>(x, Wqkv, Wproj,
                                                             X1, W1, WP1);
  gemm_bf_qkv<<<dim3(6 * 512), 256, 0, stream>>>(X1, W1, bqkv, Qbf, Kbf, Vbf);
  attn_proj<<<dim3(B_SZ * NB), 256, 0, stream>>>(Qbf, Kbf, Vbf, amask, efeat,
                                                 Wgate, bgate, WP1, bproj, out);
}

// Round 20
// 139.114 us; speedup vs baseline: 1.0570x; 1.0570x over previous
//
#include <hip/hip_runtime.h>
#include <cstdint>
#include <cstddef>

#define B_SZ 2
#define N_SEQ 32768
#define NB 2048
#define HD 32
#define LQ 16
#define KCNT 17
#define M_ROWS 65536
#define SCALE_F 0.17677669529663687f /* 32^-0.5 */

typedef __attribute__((ext_vector_type(8))) short sv8;
typedef __attribute__((ext_vector_type(4))) short sv4;
typedef __attribute__((ext_vector_type(4))) float f4;

__device__ __forceinline__ short f2bf(float f) {
  unsigned u = __builtin_bit_cast(unsigned, f);
  u = (u + 0x7FFFu + ((u >> 16) & 1u)) >> 16;
  return (short)u;
}
__device__ __forceinline__ float bf2f(short s) {
  unsigned u = ((unsigned)(unsigned short)s) << 16;
  return __builtin_bit_cast(float, u);
}
__device__ __forceinline__ void gload16(const void* g, void* l) {
  __builtin_amdgcn_global_load_lds(
      (const __attribute__((address_space(1))) unsigned int*)g,
      (__attribute__((address_space(3))) unsigned int*)l, 16, 0, 0);
}
__device__ __forceinline__ f4 mfma16(sv8 a, sv8 b, f4 c) {
  return __builtin_amdgcn_mfma_f32_16x16x32_bf16(a, b, c, 0, 0, 0);
}

// fused prep: cast X (4194304 f4), Wqkv (49152 f4), Wproj (16384 f4) to bf16
__global__ __launch_bounds__(256) void cast_all(
    const float* __restrict__ x, const float* __restrict__ wq,
    const float* __restrict__ wp, short* __restrict__ X1,
    short* __restrict__ W1, short* __restrict__ WP1) {
  const int i = blockIdx.x * 256 + threadIdx.x;
  const float* src;
  short* dst;
  int off;
  if (i < 4194304) { src = x; dst = X1; off = i; }
  else if (i < 4194304 + 49152) { src = wq; dst = W1; off = i - 4194304; }
  else if (i < 4194304 + 49152 + 16384) { src = wp; dst = WP1; off = i - 4194304 - 49152; }
  else return;
  float4 v = ((const float4*)src)[off];
  sv4 h = {f2bf(v.x), f2bf(v.y), f2bf(v.z), f2bf(v.w)};
  *(sv4*)&dst[(size_t)off * 4] = h;
}

// ---- QKV GEMM: 8-wave 256x128 tile. Per-wave acc stays 4x4 (VGPR ~76);
// blocks halved (1536), staging bytes/output -27%, barriers amortized 2x.
// 2-buffer counted-vmcnt K-loop (vmcnt(3): 3 loads/wave/chunk in flight).
// Epilogue: two 128-row halves through the 32 KB A-staging union
// (swizzled LDS -> fully coalesced sv8 stores). XCD-chunked swizzle.
__global__ __launch_bounds__(512) void gemm_bf_qkv(
    const short* __restrict__ A1, const short* __restrict__ B1,
    const float* __restrict__ bias, short* __restrict__ Qbf,
    short* __restrict__ Kbf, short* __restrict__ Vbf) {
  __shared__ __align__(16) short As[2][256][32];  // 32 KB
  __shared__ __align__(16) short Bs[2][128][32];  // 16 KB
  const int tid = threadIdx.x;
  const int w = tid >> 6, l = tid & 63;
  const int wm = w >> 1, wn = w & 1;  // wm 0..3 (64-row strip), wn 0..1
  const int bid = blockIdx.x;
  const int chunkc = (6 * 256) >> 3;  // 192
  const int lbid = (bid & 7) * chunkc + (bid >> 3);
  const int nti = lbid % 6, mti = lbid / 6;
  const int m0 = mti * 256, n0 = nti * 128;
  const int lr = l >> 2, lc = (l & 3) * 8;
  const int fr = l & 15, kg = (l >> 4) * 8;
  f4 acc[4][4] = {};
  // prologue: chunk 0 (A: 2 issues of 8 KB, B: 1 issue)
#pragma unroll
  for (int i = 0; i < 2; ++i)
    gload16(A1 + (size_t)(m0 + i * 128 + w * 16 + lr) * 256 + lc,
            (void*)&As[0][i * 128 + w * 16][0]);
  gload16(B1 + (size_t)(n0 + w * 16 + lr) * 256 + lc, (void*)&Bs[0][w * 16][0]);
  asm volatile("s_waitcnt vmcnt(0)" ::: "memory");
  __builtin_amdgcn_s_barrier();
  int cur = 0;
  for (int s = 0; s < 8; ++s) {
    if (s < 7) {
      const int sk = (s + 1) * 32;
#pragma unroll
      for (int i = 0; i < 2; ++i)
        gload16(A1 + (size_t)(m0 + i * 128 + w * 16 + lr) * 256 + sk + lc,
                (void*)&As[cur ^ 1][i * 128 + w * 16][0]);
      gload16(B1 + (size_t)(n0 + w * 16 + lr) * 256 + sk + lc,
              (void*)&Bs[cur ^ 1][w * 16][0]);
    }
    if (s > 0) {
      if (s < 7) asm volatile("s_waitcnt vmcnt(3)" ::: "memory");
      else asm volatile("s_waitcnt vmcnt(0)" ::: "memory");
      __builtin_amdgcn_s_barrier();
    }
    sv8 fa[4], fb[4];
#pragma unroll
    for (int t = 0; t < 4; ++t) {
      fa[t] = *(const sv8*)&As[cur][wm * 64 + t * 16 + fr][kg];
      fb[t] = *(const sv8*)&Bs[cur][wn * 64 + t * 16 + fr][kg];
    }
#pragma unroll
    for (int mt = 0; mt < 4; ++mt)
#pragma unroll
      for (int nt2 = 0; nt2 < 4; ++nt2)
        acc[mt][nt2] = mfma16(fa[mt], fb[nt2], acc[mt][nt2]);
    asm volatile("s_waitcnt lgkmcnt(0)" ::: "memory");
    __builtin_amdgcn_s_barrier();
    cur ^= 1;
  }
  // epilogue: two 128-row halves via swizzled 32 KB LDS (the As union)
  short* Lout = (short*)As;
  short* dst = (nti < 2) ? Qbf : ((nti < 4) ? Kbf : Vbf);
  const int nnb = (nti & 1) * 128;
  const int r0 = (l >> 4) * 4;
  const int rrow = tid >> 4, seg = (tid & 15) * 8;  // rrow 0..31
#pragma unroll
  for (int half = 0; half < 2; ++half) {
    if ((wm >> 1) == half) {
      const int mb = (wm & 1) * 64;  // row base within half
#pragma unroll
      for (int mt = 0; mt < 4; ++mt)
#pragma unroll
        for (int nt2 = 0; nt2 < 4; ++nt2) {
          const int n = wn * 64 + nt2 * 16 + fr;
          const float bv = bias[n0 + n];
#pragma unroll
          for (int j = 0; j < 4; ++j) {
            const int m = mb + mt * 16 + r0 + j;
            Lout[m * 128 + (n ^ ((m & 7) << 3))] = f2bf(acc[mt][nt2][j] + bv);
          }
        }
    }
    __builtin_amdgcn_s_barrier();
#pragma unroll
    for (int p = 0; p < 4; ++p) {
      const int row = p * 32 + rrow;
      sv8 v = *(const sv8*)&Lout[row * 128 + (seg ^ ((row & 7) << 3))];
      *(sv8*)&dst[(size_t)(m0 + half * 128 + row) * 256 + nnb + seg] = v;
    }
    __builtin_amdgcn_s_barrier();  // WAR: reads done before half-1 overwrite
  }
}

// ---- proj GEMM: 2-buffer bf16 128x128 (round-15/18 proven), fp32 out ----
__global__ __launch_bounds__(256) void gemm_proj1(
    const short* __restrict__ A1, const short* __restrict__ B1,
    const float* __restrict__ bias, float* __restrict__ C) {
  __shared__ __align__(16) short Ahs[2][128][32];
  __shared__ __align__(16) short Bhs[2][128][32];
  const int tid = threadIdx.x;
  const int w = tid >> 6, l = tid & 63;
  const int wm = w >> 1, wn = w & 1;
  const int bid = blockIdx.x;
  const int chunkc = (2 * 512) >> 3;
  const int lbid = (bid & 7) * chunkc + (bid >> 3);
  const int nti = lbid % 2, mti = lbid / 2;
  const int m0 = mti * 128, n0 = nti * 128;
  const int lr = l >> 2, lc = (l & 3) * 8;
  const int fr = l & 15, kg = (l >> 4) * 8;
  f4 acc[4][4] = {};
#pragma unroll
  for (int i = 0; i < 2; ++i) {
    const int row = w * 32 + i * 16;
    gload16(A1 + (size_t)(m0 + row + lr) * 256 + lc, (void*)&Ahs[0][row][0]);
    gload16(B1 + (size_t)(n0 + row + lr) * 256 + lc, (void*)&Bhs[0][row][0]);
  }
  asm volatile("s_waitcnt vmcnt(0)" ::: "memory");
  __builtin_amdgcn_s_barrier();
  int cur = 0;
  for (int s = 0; s < 8; ++s) {
    if (s < 7) {
      const int sk = (s + 1) * 32;
#pragma unroll
      for (int i = 0; i < 2; ++i) {
        const int row = w * 32 + i * 16;
        gload16(A1 + (size_t)(m0 + row + lr) * 256 + sk + lc,
                (void*)&Ahs[cur ^ 1][row][0]);
        gload16(B1 + (size_t)(n0 + row + lr) * 256 + sk + lc,
                (void*)&Bhs[cur ^ 1][row][0]);
      }
    }
    if (s > 0) {
      if (s < 7) asm volatile("s_waitcnt vmcnt(4)" ::: "memory");
      else asm volatile("s_waitcnt vmcnt(0)" ::: "memory");
      __builtin_amdgcn_s_barrier();
    }
    sv8 fa[4], fb[4];
#pragma unroll
    for (int t = 0; t < 4; ++t) {
      fa[t] = *(const sv8*)&Ahs[cur][wm * 64 + t * 16 + fr][kg];
      fb[t] = *(const sv8*)&Bhs[cur][wn * 64 + t * 16 + fr][kg];
    }
#pragma unroll
    for (int mt = 0; mt < 4; ++mt)
#pragma unroll
      for (int nt2 = 0; nt2 < 4; ++nt2)
        acc[mt][nt2] = mfma16(fa[mt], fb[nt2], acc[mt][nt2]);
    asm volatile("s_waitcnt lgkmcnt(0)" ::: "memory");
    __builtin_amdgcn_s_barrier();
    cur ^= 1;
  }
  const int r0 = (l >> 4) * 4;
#pragma unroll
  for (int mt = 0; mt < 4; ++mt)
#pragma unroll
    for (int nt2 = 0; nt2 < 4; ++nt2) {
      const int n = n0 + wn * 64 + nt2 * 16 + fr;
      const float bv = bias[n];
      const size_t mb = (size_t)(m0 + wm * 64 + mt * 16 + r0);
#pragma unroll
      for (int j = 0; j < 4; ++j) C[(mb + j) * 256 + n] = acc[mt][nt2][j] + bv;
    }
}

// ---- attn_v7b: MFMA attention, LDS-diet (5 blocks/CU) — round-18 proven ----
__global__ __launch_bounds__(256, 5) void attn_v7(
    const short* __restrict__ Qb, const short* __restrict__ Kb,
    const short* __restrict__ Vb, const int* __restrict__ amask,
    const float* __restrict__ efeat, const float* __restrict__ Wgate,
    const float* __restrict__ bgate, short* __restrict__ AO) {
  __shared__ __align__(16) short Kl[16 * 264];
  __shared__ __align__(16) short Vl[16 * 264];
  __shared__ __align__(16) short Ol[16 * 264];
  __shared__ float4 Es[LQ * KCNT];
  __shared__ int Ms[LQ * KCNT];

  const int tid = threadIdx.x, g = blockIdx.x;
  const int b = g >> 11, nb = g & (NB - 1);
  const size_t tok0 = (size_t)(b * N_SEQ + nb * LQ);
  const int w = tid >> 6, l = tid & 63;
  const int ln = l & 15, lg = l >> 4;
  const f4 fzero = {0.f, 0.f, 0.f, 0.f};

  sv8 qf[2];
#pragma unroll
  for (int hh = 0; hh < 2; ++hh) {
    const int h = w * 2 + hh;
    qf[hh] = *(const sv8*)(Qb + (tok0 + ln) * 256 + h * 32 + lg * 8);
  }

#pragma unroll
  for (int i = 0; i < 2; ++i) {
    const int f = tid + i * 256;
    const int t = f >> 5, c8 = (f & 31) * 8;
    *(sv8*)&Kl[t * 264 + c8] = *(const sv8*)(Kb + (tok0 + t) * 256 + c8);
    *(sv8*)&Vl[t * 264 + c8] = *(const sv8*)(Vb + (tok0 + t) * 256 + c8);
  }
  {
    const float4* esrc = (const float4*)(efeat + (size_t)nb * LQ * KCNT * 4);
    const int* msrc = amask + (size_t)nb * LQ * KCNT;
    Es[tid] = esrc[tid];
    Ms[tid] = msrc[tid];
    if (tid < LQ * KCNT - 256) {
      Es[256 + tid] = esrc[256 + tid];
      Ms[256 + tid] = msrc[256 + tid];
    }
  }
  __syncthreads();

  const int q = ln;
#pragma unroll
  for (int hh = 0; hh < 2; ++hh) {
    const int h = w * 2 + hh;
    sv8 ka = *(const sv8*)&Kl[ln * 264 + h * 32 + lg * 8];
    f4 sr = mfma16(ka, qf[hh], fzero);

    const float wg0 = Wgate[h * 4], wg1 = Wgate[h * 4 + 1];
    const float wg2 = Wgate[h * 4 + 2], wg3 = Wgate[h * 4 + 3];
    const float bg = bgate[h];

    float rs = sr[0] + sr[1] + sr[2] + sr[3];
    rs += __shfl_xor(rs, 16);
    rs += __shfl_xor(rs, 32);

    float s_[4], gt_[4];
    int vis_[4];
#pragma unroll
    for (int j = 0; j < 4; ++j) {
      const int kc = lg * 4 + j;
      float e0, e1, e2, e3;
      if (kc == q) { e0 = e1 = e2 = 0.f; e3 = 1.f; }
      else { float4 e = Es[q * KCNT + kc]; e0 = e.x; e1 = e.y; e2 = e.z; e3 = e.w; }
      const int m = Ms[q * KCNT + kc];
      vis_[j] = m;
      s_[j] = sr[j] * SCALE_F + e3;
      gt_[j] = m ? (e0 * wg0 + e1 * wg1 + e2 * wg2 + e3 * wg3 + bg) : 0.f;
    }
    const int m16 = Ms[q * KCNT + 16];
    const float s16 = rs * 0.0625f * SCALE_F + 1.0f;

    float mx = -1e30f;
#pragma unroll
    for (int j = 0; j < 4; ++j)
      if (vis_[j]) mx = fmaxf(mx, s_[j]);
    mx = fmaxf(mx, __shfl_xor(mx, 16));
    mx = fmaxf(mx, __shfl_xor(mx, 32));
    if (m16) mx = fmaxf(mx, s16);

    float p_[4], den = 0.f;
#pragma unroll
    for (int j = 0; j < 4; ++j) {
      p_[j] = vis_[j] ? __expf(s_[j] - mx) : 0.f;
      den += p_[j];
    }
    den += __shfl_xor(den, 16);
    den += __shfl_xor(den, 32);
    const float p16 = m16 ? __expf(s16 - mx) : 0.f;
    den += p16;
    const float inv = 1.f / den;
    const float gt16 = m16 ? (wg3 + bg) : 0.f;
    const float cb16 = (p16 * inv + gt16) * 0.0625f;
    float pc[4];
#pragma unroll
    for (int j = 0; j < 4; ++j) pc[j] = p_[j] * inv + gt_[j] + cb16;

    sv8 pa;
#pragma unroll
    for (int e = 0; e < 8; ++e) {
      const int kc = lg * 8 + e;
      const int src = ((kc >> 2) << 4) | q;
      const float v0 = __shfl(pc[e & 3], src);
      pa[e] = (kc < 16) ? f2bf(v0) : (short)0;
    }

#pragma unroll
    for (int t = 0; t < 2; ++t) {
      sv8 vb;
#pragma unroll
      for (int e = 0; e < 8; ++e) {
        const int vr = (lg * 8 + e) & 15;  // clamp: pa[e]=0 for kc>=16
        vb[e] = Vl[vr * 264 + h * 32 + t * 16 + ln];
      }
      f4 oacc = mfma16(pa, vb, fzero);
#pragma unroll
      for (int j = 0; j < 4; ++j)
        Ol[(lg * 4 + j) * 264 + h * 32 + t * 16 + ln] = f2bf(oacc[j]);
    }
  }
  __syncthreads();

#pragma unroll
  for (int i = 0; i < 2; ++i) {
    const int f = tid + i * 256;
    const int t = f >> 5, c8 = (f & 31) * 8;
    *(sv8*)(AO + (tok0 + t) * 256 + c8) = *(const sv8*)&Ol[t * 264 + c8];
  }
}

extern "C" void kernel_launch(void* const* d_in, const int* in_sizes, int n_in,
                              void* d_out, int out_size, void* d_ws, size_t ws_size,
                              hipStream_t stream) {
  const float* x = (const float*)d_in[0];
  const int* amask = (const int*)d_in[1];
  const float* efeat = (const float*)d_in[2];
  const float* Wqkv = (const float*)d_in[3];
  const float* bqkv = (const float*)d_in[4];
  const float* Wproj = (const float*)d_in[5];
  const float* bproj = (const float*)d_in[6];
  const float* Wgate = (const float*)d_in[7];
  const float* bgate = (const float*)d_in[8];
  float* out = (float*)d_out;

  char* ws = (char*)d_ws;
  const size_t QB_SZ = (size_t)M_ROWS * 256 * 2;  // 32 MiB each
  const size_t W1_SZ = (size_t)768 * 256 * 2;     // 384 KiB
  const size_t WP1_SZ = (size_t)256 * 256 * 2;    // 128 KiB
  if (ws_size < 5 * QB_SZ + W1_SZ + WP1_SZ) return;

  short* X1 = (short*)ws;
  short* Qbf = (short*)(ws + QB_SZ);
  short* Kbf = (short*)(ws + 2 * QB_SZ);
  short* Vbf = (short*)(ws + 3 * QB_SZ);
  short* AOh = (short*)(ws + 4 * QB_SZ);
  short* W1 = (short*)(ws + 5 * QB_SZ);
  short* WP1 = (short*)(ws + 5 * QB_SZ + W1_SZ);

  const int total_f4 = 4194304 + 49152 + 16384;
  cast_all<<<dim3((total_f4 + 255) / 256), 256, 0, stream>>>(x, Wqkv, Wproj,
                                                             X1, W1, WP1);
  gemm_bf_qkv<<<dim3(6 * 256), 512, 0, stream>>>(X1, W1, bqkv, Qbf, Kbf, Vbf);
  attn_v7<<<dim3(B_SZ * NB), 256, 0, stream>>>(Qbf, Kbf, Vbf, amask, efeat,
                                               Wgate, bgate, AOh);
  gemm_proj1<<<dim3(2 * 512), 256, 0, stream>>>(AOh, WP1, bproj, out);
}

// Round 21
// 122.658 us; speedup vs baseline: 1.1988x; 1.1342x over previous
//
#include <hip/hip_runtime.h>
#include <cstdint>
#include <cstddef>

#define B_SZ 2
#define N_SEQ 32768
#define NB 2048
#define HD 32
#define LQ 16
#define KCNT 17
#define M_ROWS 65536
#define SCALE_F 0.17677669529663687f /* 32^-0.5 */

typedef __attribute__((ext_vector_type(8))) short sv8;
typedef __attribute__((ext_vector_type(4))) short sv4;
typedef __attribute__((ext_vector_type(4))) float f4;

__device__ __forceinline__ short f2bf(float f) {
  unsigned u = __builtin_bit_cast(unsigned, f);
  u = (u + 0x7FFFu + ((u >> 16) & 1u)) >> 16;
  return (short)u;
}
__device__ __forceinline__ float bf2f(short s) {
  unsigned u = ((unsigned)(unsigned short)s) << 16;
  return __builtin_bit_cast(float, u);
}
__device__ __forceinline__ void gload16(const void* g, void* l) {
  __builtin_amdgcn_global_load_lds(
      (const __attribute__((address_space(1))) unsigned int*)g,
      (__attribute__((address_space(3))) unsigned int*)l, 16, 0, 0);
}
__device__ __forceinline__ f4 mfma16(sv8 a, sv8 b, f4 c) {
  return __builtin_amdgcn_mfma_f32_16x16x32_bf16(a, b, c, 0, 0, 0);
}

// fused prep: cast X (4194304 f4), Wqkv (49152 f4), Wproj (16384 f4) to bf16
__global__ __launch_bounds__(256) void cast_all(
    const float* __restrict__ x, const float* __restrict__ wq,
    const float* __restrict__ wp, short* __restrict__ X1,
    short* __restrict__ W1, short* __restrict__ WP1) {
  const int i = blockIdx.x * 256 + threadIdx.x;
  const float* src;
  short* dst;
  int off;
  if (i < 4194304) { src = x; dst = X1; off = i; }
  else if (i < 4194304 + 49152) { src = wq; dst = W1; off = i - 4194304; }
  else if (i < 4194304 + 49152 + 16384) { src = wp; dst = WP1; off = i - 4194304 - 49152; }
  else return;
  float4 v = ((const float4*)src)[off];
  sv4 h = {f2bf(v.x), f2bf(v.y), f2bf(v.z), f2bf(v.w)};
  *(sv4*)&dst[(size_t)off * 4] = h;
}

// ---- QKV GEMM: 2-buffer counted-vmcnt K-loop + LDS-staged coalesced
// epilogue (round-18 proven, 49 us). 128x128 tile, 4 waves. ----
__global__ __launch_bounds__(256) void gemm_bf_qkv(
    const short* __restrict__ A1, const short* __restrict__ B1,
    const float* __restrict__ bias, short* __restrict__ Qbf,
    short* __restrict__ Kbf, short* __restrict__ Vbf) {
  __shared__ __align__(16) short LB[2][2][128][32];  // [buf][A|B][row][col]
  const int tid = threadIdx.x;
  const int w = tid >> 6, l = tid & 63;
  const int wm = w >> 1, wn = w & 1;
  const int bid = blockIdx.x;
  const int chunkc = (6 * 512) >> 3;
  const int lbid = (bid & 7) * chunkc + (bid >> 3);
  const int nti = lbid % 6, mti = lbid / 6;
  const int m0 = mti * 128, n0 = nti * 128;
  const int lr = l >> 2, lc = (l & 3) * 8;
  const int fr = l & 15, kg = (l >> 4) * 8;
  f4 acc[4][4] = {};
#pragma unroll
  for (int i = 0; i < 2; ++i) {
    const int row = w * 32 + i * 16;
    gload16(A1 + (size_t)(m0 + row + lr) * 256 + lc, (void*)&LB[0][0][row][0]);
    gload16(B1 + (size_t)(n0 + row + lr) * 256 + lc, (void*)&LB[0][1][row][0]);
  }
  asm volatile("s_waitcnt vmcnt(0)" ::: "memory");
  __builtin_amdgcn_s_barrier();
  int cur = 0;
  for (int s = 0; s < 8; ++s) {
    if (s < 7) {
      const int sk = (s + 1) * 32;
#pragma unroll
      for (int i = 0; i < 2; ++i) {
        const int row = w * 32 + i * 16;
        gload16(A1 + (size_t)(m0 + row + lr) * 256 + sk + lc,
                (void*)&LB[cur ^ 1][0][row][0]);
        gload16(B1 + (size_t)(n0 + row + lr) * 256 + sk + lc,
                (void*)&LB[cur ^ 1][1][row][0]);
      }
    }
    if (s > 0) {
      if (s < 7) asm volatile("s_waitcnt vmcnt(4)" ::: "memory");
      else asm volatile("s_waitcnt vmcnt(0)" ::: "memory");
      __builtin_amdgcn_s_barrier();
    }
    sv8 fa[4], fb[4];
#pragma unroll
    for (int t = 0; t < 4; ++t) {
      fa[t] = *(const sv8*)&LB[cur][0][wm * 64 + t * 16 + fr][kg];
      fb[t] = *(const sv8*)&LB[cur][1][wn * 64 + t * 16 + fr][kg];
    }
#pragma unroll
    for (int mt = 0; mt < 4; ++mt)
#pragma unroll
      for (int nt2 = 0; nt2 < 4; ++nt2)
        acc[mt][nt2] = mfma16(fa[mt], fb[nt2], acc[mt][nt2]);
    asm volatile("s_waitcnt lgkmcnt(0)" ::: "memory");
    __builtin_amdgcn_s_barrier();
    cur ^= 1;
  }
  short* Lout = &LB[0][0][0][0];  // 128x128 shorts = 32 KB
  const int r0 = (l >> 4) * 4;
#pragma unroll
  for (int mt = 0; mt < 4; ++mt)
#pragma unroll
    for (int nt2 = 0; nt2 < 4; ++nt2) {
      const int n = wn * 64 + nt2 * 16 + fr;
      const float bv = bias[n0 + n];
#pragma unroll
      for (int j = 0; j < 4; ++j) {
        const int m = wm * 64 + mt * 16 + r0 + j;
        Lout[m * 128 + (n ^ ((m & 7) << 3))] = f2bf(acc[mt][nt2][j] + bv);
      }
    }
  __builtin_amdgcn_s_barrier();
  short* dst = (nti < 2) ? Qbf : ((nti < 4) ? Kbf : Vbf);
  const int nnb = (nti & 1) * 128;
  const int rrow = tid >> 4, seg = (tid & 15) * 8;
#pragma unroll
  for (int p = 0; p < 8; ++p) {
    const int row = p * 16 + rrow;
    sv8 v = *(const sv8*)&Lout[row * 128 + (seg ^ ((row & 7) << 3))];
    *(sv8*)&dst[(size_t)(m0 + row) * 256 + nnb + seg] = v;
  }
}

// ---- proj GEMM: 2-buffer bf16 128x128 (round-15/18 proven), fp32 out ----
__global__ __launch_bounds__(256) void gemm_proj1(
    const short* __restrict__ A1, const short* __restrict__ B1,
    const float* __restrict__ bias, float* __restrict__ C) {
  __shared__ __align__(16) short Ahs[2][128][32];
  __shared__ __align__(16) short Bhs[2][128][32];
  const int tid = threadIdx.x;
  const int w = tid >> 6, l = tid & 63;
  const int wm = w >> 1, wn = w & 1;
  const int bid = blockIdx.x;
  const int chunkc = (2 * 512) >> 3;
  const int lbid = (bid & 7) * chunkc + (bid >> 3);
  const int nti = lbid % 2, mti = lbid / 2;
  const int m0 = mti * 128, n0 = nti * 128;
  const int lr = l >> 2, lc = (l & 3) * 8;
  const int fr = l & 15, kg = (l >> 4) * 8;
  f4 acc[4][4] = {};
#pragma unroll
  for (int i = 0; i < 2; ++i) {
    const int row = w * 32 + i * 16;
    gload16(A1 + (size_t)(m0 + row + lr) * 256 + lc, (void*)&Ahs[0][row][0]);
    gload16(B1 + (size_t)(n0 + row + lr) * 256 + lc, (void*)&Bhs[0][row][0]);
  }
  asm volatile("s_waitcnt vmcnt(0)" ::: "memory");
  __builtin_amdgcn_s_barrier();
  int cur = 0;
  for (int s = 0; s < 8; ++s) {
    if (s < 7) {
      const int sk = (s + 1) * 32;
#pragma unroll
      for (int i = 0; i < 2; ++i) {
        const int row = w * 32 + i * 16;
        gload16(A1 + (size_t)(m0 + row + lr) * 256 + sk + lc,
                (void*)&Ahs[cur ^ 1][row][0]);
        gload16(B1 + (size_t)(n0 + row + lr) * 256 + sk + lc,
                (void*)&Bhs[cur ^ 1][row][0]);
      }
    }
    if (s > 0) {
      if (s < 7) asm volatile("s_waitcnt vmcnt(4)" ::: "memory");
      else asm volatile("s_waitcnt vmcnt(0)" ::: "memory");
      __builtin_amdgcn_s_barrier();
    }
    sv8 fa[4], fb[4];
#pragma unroll
    for (int t = 0; t < 4; ++t) {
      fa[t] = *(const sv8*)&Ahs[cur][wm * 64 + t * 16 + fr][kg];
      fb[t] = *(const sv8*)&Bhs[cur][wn * 64 + t * 16 + fr][kg];
    }
#pragma unroll
    for (int mt = 0; mt < 4; ++mt)
#pragma unroll
      for (int nt2 = 0; nt2 < 4; ++nt2)
        acc[mt][nt2] = mfma16(fa[mt], fb[nt2], acc[mt][nt2]);
    asm volatile("s_waitcnt lgkmcnt(0)" ::: "memory");
    __builtin_amdgcn_s_barrier();
    cur ^= 1;
  }
  const int r0 = (l >> 4) * 4;
#pragma unroll
  for (int mt = 0; mt < 4; ++mt)
#pragma unroll
    for (int nt2 = 0; nt2 < 4; ++nt2) {
      const int n = n0 + wn * 64 + nt2 * 16 + fr;
      const float bv = bias[n];
      const size_t mb = (size_t)(m0 + wm * 64 + mt * 16 + r0);
#pragma unroll
      for (int j = 0; j < 4; ++j) C[(mb + j) * 256 + n] = acc[mt][nt2][j] + bv;
    }
}

// ---- attn_v8: MFMA attention. Ol ALIASES Kl (K dead after score MFMAs,
// which are hoisted for both heads before an extra barrier). LDS 21.8 KB
// -> 7 blocks/CU. Grid XCD-affinity swizzled to match gemm's M-panel
// ownership (tokens [8192c, 8192(c+1)) on XCD c) for L2 reuse.
__global__ __launch_bounds__(256, 7) void attn_v8(
    const short* __restrict__ Qb, const short* __restrict__ Kb,
    const short* __restrict__ Vb, const int* __restrict__ amask,
    const float* __restrict__ efeat, const float* __restrict__ Wgate,
    const float* __restrict__ bgate, short* __restrict__ AO) {
  __shared__ __align__(16) short Kl[16 * 264];  // also Ol after scores
  __shared__ __align__(16) short Vl[16 * 264];
  __shared__ float4 Es[LQ * KCNT];
  __shared__ int Ms[LQ * KCNT];
  short* Ol = Kl;

  const int tid = threadIdx.x;
  const int bid = blockIdx.x;
  const int g = (bid & 7) * 512 + (bid >> 3);  // XCD-affinity (4096 = 8*512)
  const int b = g >> 11, nb = g & (NB - 1);
  const size_t tok0 = (size_t)(b * N_SEQ + nb * LQ);
  const int w = tid >> 6, l = tid & 63;
  const int ln = l & 15, lg = l >> 4;
  const f4 fzero = {0.f, 0.f, 0.f, 0.f};

  sv8 qf[2];
#pragma unroll
  for (int hh = 0; hh < 2; ++hh) {
    const int h = w * 2 + hh;
    qf[hh] = *(const sv8*)(Qb + (tok0 + ln) * 256 + h * 32 + lg * 8);
  }

#pragma unroll
  for (int i = 0; i < 2; ++i) {
    const int f = tid + i * 256;
    const int t = f >> 5, c8 = (f & 31) * 8;
    *(sv8*)&Kl[t * 264 + c8] = *(const sv8*)(Kb + (tok0 + t) * 256 + c8);
    *(sv8*)&Vl[t * 264 + c8] = *(const sv8*)(Vb + (tok0 + t) * 256 + c8);
  }
  {
    const float4* esrc = (const float4*)(efeat + (size_t)nb * LQ * KCNT * 4);
    const int* msrc = amask + (size_t)nb * LQ * KCNT;
    Es[tid] = esrc[tid];
    Ms[tid] = msrc[tid];
    if (tid < LQ * KCNT - 256) {
      Es[256 + tid] = esrc[256 + tid];
      Ms[256 + tid] = msrc[256 + tid];
    }
  }
  __syncthreads();

  const int q = ln;
  // scores for BOTH heads first (all Kl reads complete before Ol overwrite)
  sv8 ka0 = *(const sv8*)&Kl[ln * 264 + (w * 2 + 0) * 32 + lg * 8];
  sv8 ka1 = *(const sv8*)&Kl[ln * 264 + (w * 2 + 1) * 32 + lg * 8];
  const f4 sr0 = mfma16(ka0, qf[0], fzero);
  const f4 sr1 = mfma16(ka1, qf[1], fzero);
  __syncthreads();  // Kl dead; Ol (= Kl) writable

#pragma unroll
  for (int hh = 0; hh < 2; ++hh) {
    const int h = w * 2 + hh;
    const f4 sr = (hh == 0) ? sr0 : sr1;  // hh compile-time (full unroll)

    const float wg0 = Wgate[h * 4], wg1 = Wgate[h * 4 + 1];
    const float wg2 = Wgate[h * 4 + 2], wg3 = Wgate[h * 4 + 3];
    const float bg = bgate[h];

    float rs = sr[0] + sr[1] + sr[2] + sr[3];
    rs += __shfl_xor(rs, 16);
    rs += __shfl_xor(rs, 32);

    float s_[4], gt_[4];
    int vis_[4];
#pragma unroll
    for (int j = 0; j < 4; ++j) {
      const int kc = lg * 4 + j;
      float e0, e1, e2, e3;
      if (kc == q) { e0 = e1 = e2 = 0.f; e3 = 1.f; }
      else { float4 e = Es[q * KCNT + kc]; e0 = e.x; e1 = e.y; e2 = e.z; e3 = e.w; }
      const int m = Ms[q * KCNT + kc];
      vis_[j] = m;
      s_[j] = sr[j] * SCALE_F + e3;
      gt_[j] = m ? (e0 * wg0 + e1 * wg1 + e2 * wg2 + e3 * wg3 + bg) : 0.f;
    }
    const int m16 = Ms[q * KCNT + 16];
    const float s16 = rs * 0.0625f * SCALE_F + 1.0f;

    float mx = -1e30f;
#pragma unroll
    for (int j = 0; j < 4; ++j)
      if (vis_[j]) mx = fmaxf(mx, s_[j]);
    mx = fmaxf(mx, __shfl_xor(mx, 16));
    mx = fmaxf(mx, __shfl_xor(mx, 32));
    if (m16) mx = fmaxf(mx, s16);

    float p_[4], den = 0.f;
#pragma unroll
    for (int j = 0; j < 4; ++j) {
      p_[j] = vis_[j] ? __expf(s_[j] - mx) : 0.f;
      den += p_[j];
    }
    den += __shfl_xor(den, 16);
    den += __shfl_xor(den, 32);
    const float p16 = m16 ? __expf(s16 - mx) : 0.f;
    den += p16;
    const float inv = 1.f / den;
    const float gt16 = m16 ? (wg3 + bg) : 0.f;
    const float cb16 = (p16 * inv + gt16) * 0.0625f;
    float pc[4];
#pragma unroll
    for (int j = 0; j < 4; ++j) pc[j] = p_[j] * inv + gt_[j] + cb16;

    sv8 pa;
#pragma unroll
    for (int e = 0; e < 8; ++e) {
      const int kc = lg * 8 + e;
      const int src = ((kc >> 2) << 4) | q;
      const float v0 = __shfl(pc[e & 3], src);
      pa[e] = (kc < 16) ? f2bf(v0) : (short)0;
    }

#pragma unroll
    for (int t = 0; t < 2; ++t) {
      sv8 vb;
#pragma unroll
      for (int e = 0; e < 8; ++e) {
        const int vr = (lg * 8 + e) & 15;  // clamp: pa[e]=0 for kc>=16
        vb[e] = Vl[vr * 264 + h * 32 + t * 16 + ln];
      }
      f4 oacc = mfma16(pa, vb, fzero);
#pragma unroll
      for (int j = 0; j < 4; ++j)
        Ol[(lg * 4 + j) * 264 + h * 32 + t * 16 + ln] = f2bf(oacc[j]);
    }
  }
  __syncthreads();

#pragma unroll
  for (int i = 0; i < 2; ++i) {
    const int f = tid + i * 256;
    const int t = f >> 5, c8 = (f & 31) * 8;
    *(sv8*)(AO + (tok0 + t) * 256 + c8) = *(const sv8*)&Ol[t * 264 + c8];
  }
}

extern "C" void kernel_launch(void* const* d_in, const int* in_sizes, int n_in,
                              void* d_out, int out_size, void* d_ws, size_t ws_size,
                              hipStream_t stream) {
  const float* x = (const float*)d_in[0];
  const int* amask = (const int*)d_in[1];
  const float* efeat = (const float*)d_in[2];
  const float* Wqkv = (const float*)d_in[3];
  const float* bqkv = (const float*)d_in[4];
  const float* Wproj = (const float*)d_in[5];
  const float* bproj = (const float*)d_in[6];
  const float* Wgate = (const float*)d_in[7];
  const float* bgate = (const float*)d_in[8];
  float* out = (float*)d_out;

  char* ws = (char*)d_ws;
  const size_t QB_SZ = (size_t)M_ROWS * 256 * 2;  // 32 MiB each
  const size_t W1_SZ = (size_t)768 * 256 * 2;     // 384 KiB
  const size_t WP1_SZ = (size_t)256 * 256 * 2;    // 128 KiB
  if (ws_size < 5 * QB_SZ + W1_SZ + WP1_SZ) return;

  short* X1 = (short*)ws;
  short* Qbf = (short*)(ws + QB_SZ);
  short* Kbf = (short*)(ws + 2 * QB_SZ);
  short* Vbf = (short*)(ws + 3 * QB_SZ);
  short* AOh = (short*)(ws + 4 * QB_SZ);
  short* W1 = (short*)(ws + 5 * QB_SZ);
  short* WP1 = (short*)(ws + 5 * QB_SZ + W1_SZ);

  const int total_f4 = 4194304 + 49152 + 16384;
  cast_all<<<dim3((total_f4 + 255) / 256), 256, 0, stream>>>(x, Wqkv, Wproj,
                                                             X1, W1, WP1);
  gemm_bf_qkv<<<dim3(6 * 512), 256, 0, stream>>>(X1, W1, bqkv, Qbf, Kbf, Vbf);
  attn_v8<<<dim3(B_SZ * NB), 256, 0, stream>>>(Qbf, Kbf, Vbf, amask, efeat,
                                               Wgate, bgate, AOh);
  gemm_proj1<<<dim3(2 * 512), 256, 0, stream>>>(AOh, WP1, bproj, out);
}